// Round 5
// baseline (560.858 us; speedup 1.0000x reference)
//
#include <hip/hip_runtime.h>
#include <hip/hip_bf16.h>

// Problem constants
#define BB 32
#define C1 128
#define SS 1024        // H*W
#define DD 256
#define NHH 8
#define DHH 32
#define KSEL 66        // ceil(0.0005*128*32*32)
#define TRIPLE 768
#define SELFLAG 0x40000000u

typedef __attribute__((ext_vector_type(8))) short bf16x8;
typedef __attribute__((ext_vector_type(4))) short bf16x4;
typedef __attribute__((ext_vector_type(4))) float f32x4;

__device__ inline short f2bf(float f) {
  union { __hip_bfloat16 h; unsigned short u; } c;
  c.h = __float2bfloat16(f);
  return (short)c.u;
}
__device__ inline float bf2f(short s) {
  union { float f; unsigned u; } c;
  c.u = ((unsigned)(unsigned short)s) << 16;
  return c.f;
}
// pack bf16(lo),bf16(hi) into one dword via byte-perm (RTZ truncation)
__device__ inline unsigned pk2(float hi, float lo) {
  return __builtin_amdgcn_perm(__float_as_uint(hi), __float_as_uint(lo), 0x07060302u);
}

// ---------------------------------------------------------------------------
// Kernel 1: 9x9 conv (cross-correlation, pad 4) + ReLU + fused level-1
// radix histogram (top 11 bits, zeros skipped) + per-batch max.
// ---------------------------------------------------------------------------
__global__ __launch_bounds__(256) void conv_relu_hist_kernel(
    const float* __restrict__ x, const float* __restrict__ w, float* __restrict__ A,
    unsigned* __restrict__ ghist1, unsigned* __restrict__ gmaxb) {
  const int bx = blockIdx.x;              // b*128 + c
  const int b = bx >> 7, c = bx & 127;
  __shared__ float xs[40 * 40];
  __shared__ float ws[81];
  __shared__ unsigned h[2048];
  __shared__ unsigned smax;
  const int t = threadIdx.x;
  for (int i = t; i < 1600; i += 256) {
    int r = i / 40, cc = i - r * 40;
    int gi = r - 4, gj = cc - 4;
    float v = 0.f;
    if (gi >= 0 && gi < 32 && gj >= 0 && gj < 32) v = x[(size_t)b * 1024 + gi * 32 + gj];
    xs[i] = v;
  }
  if (t < 81) ws[t] = w[(size_t)c * 81 + t];
  for (int i = t; i < 2048; i += 256) h[i] = 0u;
  if (t == 0) smax = 0u;
  __syncthreads();
  unsigned lmax = 0u;
#pragma unroll
  for (int i = 0; i < 4; ++i) {
    int p = t + i * 256;
    int r = p >> 5, col = p & 31;
    float acc = 0.f;
#pragma unroll
    for (int u = 0; u < 9; ++u)
#pragma unroll
      for (int v = 0; v < 9; ++v)
        acc += xs[(r + u) * 40 + col + v] * ws[u * 9 + v];
    acc = fmaxf(acc, 0.f);
    A[(size_t)bx * 1024 + p] = acc;
    unsigned bits = __float_as_uint(acc);
    if (bits > lmax) lmax = bits;
    if (bits >= (1u << 21)) atomicAdd(&h[bits >> 21], 1u);
  }
  atomicMax(&smax, lmax);
  __syncthreads();
  for (int i = t; i < 2048; i += 256)
    if (h[i]) atomicAdd(&ghist1[b * 2048 + i], h[i]);
  if (t == 0) atomicMax(&gmaxb[b], smax);
}

// ---------------------------------------------------------------------------
// Kernel 2a/2b: level-2 / level-3 radix histograms (rare-match passes)
// ---------------------------------------------------------------------------
__global__ __launch_bounds__(256) void hist2_kernel(
    const float* __restrict__ A, const unsigned* __restrict__ selv,
    unsigned* __restrict__ gh) {
  const int b = blockIdx.y, slice = blockIdx.x, t = threadIdx.x;
  const unsigned v1 = selv[b];
  __shared__ unsigned h[2048];
  for (int i = t; i < 2048; i += 256) h[i] = 0u;
  __syncthreads();
  const float* Ab = A + (size_t)b * (C1 * SS) + slice * 8192;
#pragma unroll 4
  for (int k = 0; k < 32; ++k) {
    unsigned bits = __float_as_uint(Ab[t + k * 256]);
    if ((bits >> 21) == v1) atomicAdd(&h[(bits >> 10) & 0x7FFu], 1u);
  }
  __syncthreads();
  for (int i = t; i < 2048; i += 256)
    if (h[i]) atomicAdd(&gh[b * 2048 + i], h[i]);
}

__global__ __launch_bounds__(256) void hist3_kernel(
    const float* __restrict__ A, const unsigned* __restrict__ selv,
    unsigned* __restrict__ gh) {
  const int b = blockIdx.y, slice = blockIdx.x, t = threadIdx.x;
  const unsigned pref = selv[b];
  __shared__ unsigned h[1024];
  for (int i = t; i < 1024; i += 256) h[i] = 0u;
  __syncthreads();
  const float* Ab = A + (size_t)b * (C1 * SS) + slice * 8192;
#pragma unroll 4
  for (int k = 0; k < 32; ++k) {
    unsigned bits = __float_as_uint(Ab[t + k * 256]);
    if ((bits >> 10) == pref) atomicAdd(&h[bits & 0x3FFu], 1u);
  }
  __syncthreads();
  for (int i = t; i < 1024; i += 256)
    if (h[i]) atomicAdd(&gh[b * 1024 + i], h[i]);
}

// ---------------------------------------------------------------------------
// Kernel 3: radix-level selection via parallel suffix scan. One block / batch.
// ---------------------------------------------------------------------------
__global__ __launch_bounds__(1024) void sel_kernel(
    const unsigned* __restrict__ gh, unsigned* __restrict__ selv,
    unsigned* __restrict__ selr, float* __restrict__ thresh,
    int nbins, int stage) {
  const int b = blockIdx.x, t = threadIdx.x;
  __shared__ unsigned hl[2048];
  __shared__ unsigned sfx[1024];
  unsigned r = (stage == 0) ? (unsigned)KSEL : selr[b];
  unsigned vold = (stage == 0) ? 0u : selv[b];
  if (nbins == 2048) {
    hl[t] = gh[b * 2048 + t];
    hl[t + 1024] = gh[b * 2048 + t + 1024];
  } else {
    hl[t] = gh[b * 1024 + t];
  }
  __syncthreads();
  sfx[t] = (nbins == 2048) ? (hl[2 * t] + hl[2 * t + 1]) : hl[t];
  __syncthreads();
  for (int off = 1; off < 1024; off <<= 1) {
    unsigned v = (t + off < 1024) ? sfx[t + off] : 0u;
    __syncthreads();
    sfx[t] += v;
    __syncthreads();
  }
  if ((stage != 0 && vold == SELFLAG) || sfx[0] < r) {
    if (t == 0) {
      if (stage == 2) thresh[b] = 0.0f;
      else { selv[b] = SELFLAG; selr[b] = r; }
    }
    return;
  }
  unsigned Snext = (t < 1023) ? sfx[t + 1] : 0u;
  if (nbins == 2048) {
    unsigned hi = hl[2 * t + 1], lo = hl[2 * t];
    if (Snext < r && Snext + hi >= r) {
      selv[b] = (vold << 11) | (unsigned)(2 * t + 1);
      selr[b] = r - Snext;
    } else if (Snext + hi < r && Snext + hi + lo >= r) {
      selv[b] = (vold << 11) | (unsigned)(2 * t);
      selr[b] = r - Snext - hi;
    }
  } else {
    if (Snext < r && sfx[t] >= r)
      thresh[b] = __uint_as_float((vold << 10) | (unsigned)t);
  }
}

// ---------------------------------------------------------------------------
// Kernel 4: per-pixel masked channel top-8 (jax tie-break semantics).
// ---------------------------------------------------------------------------
__global__ __launch_bounds__(256) void topk_pixel_kernel(
    const float* __restrict__ A, const float* __restrict__ thresh,
    const float* __restrict__ gmaxp, float* __restrict__ out_sw,
    float* __restrict__ out_topi, int* __restrict__ kidx, float* __restrict__ kval) {
  const int bx = blockIdx.x;              // b*4 + chunk
  const int b = bx >> 2;
  const int p = ((bx & 3) << 8) + threadIdx.x;
  const float th = thresh[b];
  const float gm = gmaxp[b];
  const float scale = gm > 0.f ? 1.f / gm : 0.f;
  const float* Ab = A + (size_t)b * (C1 * SS) + p;

  float tv0 = -1.f, tv1 = -1.f, tv2 = -1.f, tv3 = -1.f, tv4 = -1.f, tv5 = -1.f, tv6 = -1.f, tv7 = -1.f;
  int ti0 = 0, ti1 = 0, ti2 = 0, ti3 = 0, ti4 = 0, ti5 = 0, ti6 = 0, ti7 = 0;
  int cnt = 0;
#pragma unroll 1
  for (int c = 0; c < C1; ++c) {
    float v = Ab[(size_t)c << 10];
    if (v >= th) {
      ++cnt;
      bool s7 = v > tv6, p7 = (v > tv7) && !s7;
      float n7 = p7 ? v : (s7 ? tv6 : tv7); int m7 = p7 ? c : (s7 ? ti6 : ti7);
      bool s6 = v > tv5, p6 = (v > tv6) && !s6;
      float n6 = p6 ? v : (s6 ? tv5 : tv6); int m6 = p6 ? c : (s6 ? ti5 : ti6);
      bool s5 = v > tv4, p5 = (v > tv5) && !s5;
      float n5 = p5 ? v : (s5 ? tv4 : tv5); int m5 = p5 ? c : (s5 ? ti4 : ti5);
      bool s4 = v > tv3, p4 = (v > tv4) && !s4;
      float n4 = p4 ? v : (s4 ? tv3 : tv4); int m4 = p4 ? c : (s4 ? ti3 : ti4);
      bool s3 = v > tv2, p3 = (v > tv3) && !s3;
      float n3 = p3 ? v : (s3 ? tv2 : tv3); int m3 = p3 ? c : (s3 ? ti2 : ti3);
      bool s2 = v > tv1, p2 = (v > tv2) && !s2;
      float n2 = p2 ? v : (s2 ? tv1 : tv2); int m2 = p2 ? c : (s2 ? ti1 : ti2);
      bool s1 = v > tv0, p1 = (v > tv1) && !s1;
      float n1 = p1 ? v : (s1 ? tv0 : tv1); int m1 = p1 ? c : (s1 ? ti0 : ti1);
      bool p0 = v > tv0;
      float n0 = p0 ? v : tv0; int m0 = p0 ? c : ti0;
      tv7 = n7; ti7 = m7; tv6 = n6; ti6 = m6; tv5 = n5; ti5 = m5; tv4 = n4; ti4 = m4;
      tv3 = n3; ti3 = m3; tv2 = n2; ti2 = m2; tv1 = n1; ti1 = m1; tv0 = n0; ti0 = m0;
    }
  }
  const int m = cnt < 8 ? cnt : 8;
  int fv[8] = {ti0, ti1, ti2, ti3, ti4, ti5, ti6, ti7};
  int fill_c = 0;
#pragma unroll
  for (int j = 0; j < 8; ++j) {
    if (j >= m) {
      bool adv = true;
      while (adv) {
        adv = false;
#pragma unroll
        for (int t2 = 0; t2 < 8; ++t2)
          if (t2 < m && fv[t2] == fill_c) adv = true;
        if (adv) ++fill_c;
      }
      fv[j] = fill_c;
      ++fill_c;
    }
  }
  ti0 = fv[0]; ti1 = fv[1]; ti2 = fv[2]; ti3 = fv[3]; ti4 = fv[4]; ti5 = fv[5]; ti6 = fv[6]; ti7 = fv[7];
  if (m <= 0) tv0 = 0.f; if (m <= 1) tv1 = 0.f; if (m <= 2) tv2 = 0.f; if (m <= 3) tv3 = 0.f;
  if (m <= 4) tv4 = 0.f; if (m <= 5) tv5 = 0.f; if (m <= 6) tv6 = 0.f; if (m <= 7) tv7 = 0.f;

  const size_t pix = (size_t)b * SS + p;
  float* tp = out_topi + pix * 8;
  tp[0] = (float)ti0; tp[1] = (float)ti1; tp[2] = (float)ti2; tp[3] = (float)ti3;
  tp[4] = (float)ti4; tp[5] = (float)ti5; tp[6] = (float)ti6; tp[7] = (float)ti7;
  int* ki = kidx + pix * 8;
  ki[0] = ti0; ki[1] = ti1; ki[2] = ti2; ki[3] = ti3; ki[4] = ti4; ki[5] = ti5; ki[6] = ti6; ki[7] = ti7;
  float* kv = kval + pix * 8;
  float sv0 = tv0 * scale, sv1 = tv1 * scale, sv2 = tv2 * scale, sv3 = tv3 * scale;
  float sv4 = tv4 * scale, sv5 = tv5 * scale, sv6 = tv6 * scale, sv7 = tv7 * scale;
  kv[0] = sv0; kv[1] = sv1; kv[2] = sv2; kv[3] = sv3; kv[4] = sv4; kv[5] = sv5; kv[6] = sv6; kv[7] = sv7;
  float* sw = out_sw + pix * C1;
  if (m > 0) sw[ti0] = sv0; if (m > 1) sw[ti1] = sv1; if (m > 2) sw[ti2] = sv2; if (m > 3) sw[ti3] = sv3;
  if (m > 4) sw[ti4] = sv4; if (m > 5) sw[ti5] = sv5; if (m > 6) sw[ti6] = sv6; if (m > 7) sw[ti7] = sv7;
}

// ---------------------------------------------------------------------------
// Kernel 5: loc_emb(b,p,d) = PE(w,d) + sum_j kval[j]*emb[kidx[j], d] -> bf16
// ---------------------------------------------------------------------------
__global__ __launch_bounds__(256) void loc_emb_kernel(
    const int* __restrict__ kidx, const float* __restrict__ kval,
    const float* __restrict__ emb, unsigned short* __restrict__ le) {
  const int pix = blockIdx.x;             // b*1024 + p
  const int d = threadIdx.x;
  const int w = pix & 31;
  const int i2 = d >> 1;
  const float div = expf((float)(2 * i2) * (-9.210340371976184f / 256.f));
  const float ang = (float)w * div;
  const float pe = (d & 1) ? cosf(ang) : sinf(ang);
  const int* ki = kidx + (size_t)pix * 8;
  const float* kv = kval + (size_t)pix * 8;
  float acc = pe;
#pragma unroll
  for (int j = 0; j < 8; ++j) acc += kv[j] * emb[(size_t)ki[j] * DD + d];
  le[(size_t)pix * DD + d] = (unsigned short)f2bf(acc);
}

// ---------------------------------------------------------------------------
// Kernel 5b: in_proj_w fp32 -> bf16
// ---------------------------------------------------------------------------
__global__ __launch_bounds__(256) void w2bf_kernel(
    const float* __restrict__ W, unsigned short* __restrict__ Wb) {
  int i = blockIdx.x * 256 + threadIdx.x;
  Wb[i] = (unsigned short)f2bf(W[i]);
}

// ---------------------------------------------------------------------------
// Kernel 6: QKV(bf16) = LE @ Wb^T + bias.  128x128 tile, 2x2 waves, K-step 32.
// ---------------------------------------------------------------------------
__global__ __launch_bounds__(256) void qkv_mfma_kernel(
    const unsigned short* __restrict__ Xb, const unsigned short* __restrict__ Wb,
    const float* __restrict__ bias, unsigned short* __restrict__ Yb) {
  __shared__ __align__(16) short As[128][40];
  __shared__ __align__(16) short Bs[128][40];
  const int bid = blockIdx.x;                 // 1536 blocks = 8 * 192
  const int wgid = (bid & 7) * 192 + (bid >> 3);
  const int nt = wgid % 6, mt = wgid / 6;
  const int t = threadIdx.x;
  const int wv = t >> 6, lane = t & 63, lg = lane >> 4, ln = lane & 15;
  const int wm = wv >> 1, wn = wv & 1;

  const int srow = t & 127;
  const int sc0 = (t >> 7) * 8, sc1 = sc0 + 16;
  const unsigned short* xr = Xb + (size_t)(mt * 128 + srow) * DD;
  const unsigned short* wr = Wb + (size_t)(nt * 128 + srow) * DD;

  f32x4 acc[4][4];
#pragma unroll
  for (int i = 0; i < 4; ++i)
#pragma unroll
    for (int j = 0; j < 4; ++j) acc[i][j] = (f32x4){0, 0, 0, 0};

  bf16x8 xa0 = *(const bf16x8*)&xr[sc0];
  bf16x8 xa1 = *(const bf16x8*)&xr[sc1];
  bf16x8 wa0 = *(const bf16x8*)&wr[sc0];
  bf16x8 wa1 = *(const bf16x8*)&wr[sc1];

  for (int k0 = 0; k0 < DD; k0 += 32) {
    __syncthreads();
    *(bf16x8*)&As[srow][sc0] = xa0;
    *(bf16x8*)&As[srow][sc1] = xa1;
    *(bf16x8*)&Bs[srow][sc0] = wa0;
    *(bf16x8*)&Bs[srow][sc1] = wa1;
    if (k0 + 32 < DD) {
      xa0 = *(const bf16x8*)&xr[k0 + 32 + sc0];
      xa1 = *(const bf16x8*)&xr[k0 + 32 + sc1];
      wa0 = *(const bf16x8*)&wr[k0 + 32 + sc0];
      wa1 = *(const bf16x8*)&wr[k0 + 32 + sc1];
    }
    __syncthreads();
    bf16x8 af[4], bfr[4];
#pragma unroll
    for (int i = 0; i < 4; ++i) af[i] = *(const bf16x8*)&As[wm * 64 + i * 16 + ln][lg * 8];
#pragma unroll
    for (int j = 0; j < 4; ++j) bfr[j] = *(const bf16x8*)&Bs[wn * 64 + j * 16 + ln][lg * 8];
#pragma unroll
    for (int i = 0; i < 4; ++i)
#pragma unroll
      for (int j = 0; j < 4; ++j)
        acc[i][j] = __builtin_amdgcn_mfma_f32_16x16x32_bf16(af[i], bfr[j], acc[i][j], 0, 0, 0);
  }
#pragma unroll
  for (int i = 0; i < 4; ++i) {
#pragma unroll
    for (int j = 0; j < 4; ++j) {
      int col = nt * 128 + wn * 64 + j * 16 + ln;
      float bcol = bias[col];
#pragma unroll
      for (int r = 0; r < 4; ++r) {
        int row = mt * 128 + wm * 64 + i * 16 + lg * 4 + r;
        Yb[(size_t)row * TRIPLE + col] = (unsigned short)f2bf(acc[i][j][r] + bcol);
      }
    }
  }
}

// ---------------------------------------------------------------------------
// Kernel 6b: V-transpose.  VT[(b*8+h)*32 + d][seq] = QKV[b][seq][512+h*32+d]
// One block per (b,h); LDS-tiled, coalesced both sides.
// ---------------------------------------------------------------------------
__global__ __launch_bounds__(256) void vtrans_kernel(
    const unsigned short* __restrict__ QKV, unsigned short* __restrict__ VT) {
  const int bh = blockIdx.x;           // b*8+h
  const int b = bh >> 3, h = bh & 7;
  const int t = threadIdx.x;
  __shared__ __align__(16) short Ls[32][136];
  const unsigned short* src0 = QKV + (size_t)b * SS * TRIPLE + 2 * DD + h * DHH;
  for (int chunk = 0; chunk < 8; ++chunk) {
    if (chunk) __syncthreads();
#pragma unroll
    for (int u = 0; u < 2; ++u) {
      int unit = t + u * 256;          // 0..511
      int key = unit & 127, dg = unit >> 7;
      bf16x8 v = *(const bf16x8*)(src0 + (size_t)(chunk * 128 + key) * TRIPLE + dg * 8);
#pragma unroll
      for (int j = 0; j < 8; ++j) Ls[dg * 8 + j][key] = v[j];
    }
    __syncthreads();
#pragma unroll
    for (int u = 0; u < 2; ++u) {
      int unit = t + u * 256;
      int d = unit >> 4, sc = unit & 15;
      bf16x8 v = *(const bf16x8*)&Ls[d][sc * 8];
      *(bf16x8*)(VT + ((size_t)bh * DHH + d) * SS + chunk * 128 + sc * 8) = v;
    }
  }
}

// ---------------------------------------------------------------------------
// Kernel 7: LDS-free bf16 MFMA flash attention (double-swapped).
// QK^T: s = mfma32(K, Q)   -> lane ln = q, 16 keys across (lg, r)
// PV:   O^T = mfma16(V^T, P) -> P fragment == s fragment (no redistribution)
// K from QKV (b128), V^T from VT (b64); softmax fully lane-local (exp2 domain).
// Block = (b,h,64-q-chunk); 4 waves x 16 q.  Zero LDS.
// ---------------------------------------------------------------------------
__global__ __launch_bounds__(256) void attn_mfma_kernel(
    const unsigned short* __restrict__ QKV, const unsigned short* __restrict__ VT,
    float* __restrict__ ctx_sum) {
  const int bid = blockIdx.x;                 // 4096 blocks = 8 * 512
  const int wgid = (bid & 7) * 512 + (bid >> 3);
  const int qc = wgid & 15;
  const int h = (wgid >> 4) & 7;
  const int b = wgid >> 7;
  const int t = threadIdx.x;
  const int wv = t >> 6, lane = t & 63, lg = lane >> 4, ln = lane & 15;

  const size_t baseB = (size_t)b * SS * TRIPLE;
  const float qsc = 0.25506973f;              // (1/sqrt(32)) * log2(e)

  // Q B-operand: col = ln (q), k = lg*8+j (d); pre-scaled into exp2 domain
  bf16x8 qf;
  {
    const unsigned short* qp = QKV + baseB + (size_t)(qc * 64 + wv * 16 + ln) * TRIPLE + h * DHH + lg * 8;
    bf16x8 qr = *(const bf16x8*)qp;
#pragma unroll
    for (int j = 0; j < 8; ++j) qf[j] = f2bf(bf2f(qr[j]) * qsc);
  }
  // K A-operand source: row = key = st*16+ln, k = d = lg*8+j
  const unsigned short* kp = QKV + baseB + DD + h * DHH + (size_t)ln * TRIPLE + lg * 8;
  // V^T A-operand source: row = d = sb*16+ln, k = key = st*16+lg*4+j
  const unsigned short* vp = VT + ((size_t)(b * NHH + h) * DHH + ln) * SS + lg * 4;

  float m = -1e30f, l = 0.f;                  // per-lane state for q = ln
  f32x4 acc0 = {0, 0, 0, 0}, acc1 = {0, 0, 0, 0};

  // prologue: K for tile 0
  bf16x8 kf0 = *(const bf16x8*)(kp + (size_t)0 * TRIPLE);
  bf16x8 kf1 = *(const bf16x8*)(kp + (size_t)16 * TRIPLE);
  bf16x8 kf2 = *(const bf16x8*)(kp + (size_t)32 * TRIPLE);
  bf16x8 kf3 = *(const bf16x8*)(kp + (size_t)48 * TRIPLE);

#pragma unroll 1
  for (int tile = 0; tile < 16; ++tile) {
    // V fragments for current tile (consumed after softmax -> latency hidden)
    const unsigned short* vt = vp + tile * 64;
    bf16x4 va00 = *(const bf16x4*)(vt + 0);
    bf16x4 va01 = *(const bf16x4*)(vt + 16);
    bf16x4 va02 = *(const bf16x4*)(vt + 32);
    bf16x4 va03 = *(const bf16x4*)(vt + 48);
    bf16x4 va10 = *(const bf16x4*)(vt + 16 * SS + 0);
    bf16x4 va11 = *(const bf16x4*)(vt + 16 * SS + 16);
    bf16x4 va12 = *(const bf16x4*)(vt + 16 * SS + 32);
    bf16x4 va13 = *(const bf16x4*)(vt + 16 * SS + 48);

    bf16x8 ka0 = kf0, ka1 = kf1, ka2 = kf2, ka3 = kf3;
    if (tile < 15) {
      const unsigned short* kn = kp + (size_t)(tile + 1) * 64 * TRIPLE;
      kf0 = *(const bf16x8*)(kn + (size_t)0 * TRIPLE);
      kf1 = *(const bf16x8*)(kn + (size_t)16 * TRIPLE);
      kf2 = *(const bf16x8*)(kn + (size_t)32 * TRIPLE);
      kf3 = *(const bf16x8*)(kn + (size_t)48 * TRIPLE);
    }

    f32x4 s0 = __builtin_amdgcn_mfma_f32_16x16x32_bf16(ka0, qf, (f32x4){0, 0, 0, 0}, 0, 0, 0);
    f32x4 s1 = __builtin_amdgcn_mfma_f32_16x16x32_bf16(ka1, qf, (f32x4){0, 0, 0, 0}, 0, 0, 0);
    f32x4 s2 = __builtin_amdgcn_mfma_f32_16x16x32_bf16(ka2, qf, (f32x4){0, 0, 0, 0}, 0, 0, 0);
    f32x4 s3 = __builtin_amdgcn_mfma_f32_16x16x32_bf16(ka3, qf, (f32x4){0, 0, 0, 0}, 0, 0, 0);

    // lane-local online softmax (exp2 domain) for q = ln
    float mx = fmaxf(fmaxf(fmaxf(s0[0], s0[1]), fmaxf(s0[2], s0[3])),
                     fmaxf(fmaxf(s1[0], s1[1]), fmaxf(s1[2], s1[3])));
    mx = fmaxf(mx, fmaxf(fmaxf(fmaxf(s2[0], s2[1]), fmaxf(s2[2], s2[3])),
                         fmaxf(fmaxf(s3[0], s3[1]), fmaxf(s3[2], s3[3]))));
    mx = fmaxf(mx, __shfl_xor(mx, 16));
    mx = fmaxf(mx, __shfl_xor(mx, 32));
    float mn = fmaxf(m, mx);
    float corr = exp2f(m - mn);
    m = mn;
    float ps = 0.f;
#pragma unroll
    for (int r = 0; r < 4; ++r) { s0[r] = exp2f(s0[r] - mn); ps += s0[r]; }
#pragma unroll
    for (int r = 0; r < 4; ++r) { s1[r] = exp2f(s1[r] - mn); ps += s1[r]; }
#pragma unroll
    for (int r = 0; r < 4; ++r) { s2[r] = exp2f(s2[r] - mn); ps += s2[r]; }
#pragma unroll
    for (int r = 0; r < 4; ++r) { s3[r] = exp2f(s3[r] - mn); ps += s3[r]; }
    ps += __shfl_xor(ps, 16);
    ps += __shfl_xor(ps, 32);
    l = l * corr + ps;

    // pack P -> bf16 (RTZ perm); fragment == B-operand of k=16 mfma directly
    union { bf16x4 v; unsigned u[2]; } pb0, pb1, pb2, pb3;
    pb0.u[0] = pk2(s0[1], s0[0]); pb0.u[1] = pk2(s0[3], s0[2]);
    pb1.u[0] = pk2(s1[1], s1[0]); pb1.u[1] = pk2(s1[3], s1[2]);
    pb2.u[0] = pk2(s2[1], s2[0]); pb2.u[1] = pk2(s2[3], s2[2]);
    pb3.u[0] = pk2(s3[1], s3[0]); pb3.u[1] = pk2(s3[3], s3[2]);

    // rescale O^T accumulators (q = ln is lane-local)
    acc0 *= corr;
    acc1 *= corr;

    // PV: O^T[d][q] += V^T[d][key] P[q][key], k=16 per st-block
    acc0 = __builtin_amdgcn_mfma_f32_16x16x16bf16_1k(va00, pb0.v, acc0, 0, 0, 0);
    acc0 = __builtin_amdgcn_mfma_f32_16x16x16bf16_1k(va01, pb1.v, acc0, 0, 0, 0);
    acc0 = __builtin_amdgcn_mfma_f32_16x16x16bf16_1k(va02, pb2.v, acc0, 0, 0, 0);
    acc0 = __builtin_amdgcn_mfma_f32_16x16x16bf16_1k(va03, pb3.v, acc0, 0, 0, 0);
    acc1 = __builtin_amdgcn_mfma_f32_16x16x16bf16_1k(va10, pb0.v, acc1, 0, 0, 0);
    acc1 = __builtin_amdgcn_mfma_f32_16x16x16bf16_1k(va11, pb1.v, acc1, 0, 0, 0);
    acc1 = __builtin_amdgcn_mfma_f32_16x16x16bf16_1k(va12, pb2.v, acc1, 0, 0, 0);
    acc1 = __builtin_amdgcn_mfma_f32_16x16x16bf16_1k(va13, pb3.v, acc1, 0, 0, 0);
  }

  // normalize (lane-local), reduce over 16 q (ln lanes), atomic add per d
  float invl = 1.f / l;
  float* cbase = &ctx_sum[b * DD + h * DHH];
#pragma unroll
  for (int r = 0; r < 4; ++r) {
    float v0 = acc0[r] * invl;
    v0 += __shfl_xor(v0, 1); v0 += __shfl_xor(v0, 2);
    v0 += __shfl_xor(v0, 4); v0 += __shfl_xor(v0, 8);
    if (ln == 0) atomicAdd(cbase + lg * 4 + r, v0);
    float v1 = acc1[r] * invl;
    v1 += __shfl_xor(v1, 1); v1 += __shfl_xor(v1, 2);
    v1 += __shfl_xor(v1, 4); v1 += __shfl_xor(v1, 8);
    if (ln == 0) atomicAdd(cbase + 16 + lg * 4 + r, v1);
  }
}

// ---------------------------------------------------------------------------
// Kernel 8: pooled(b,o) = bias[o] + sum_d (ctx_sum[b,d]/1024) * Wout[o,d]
// ---------------------------------------------------------------------------
__global__ __launch_bounds__(256) void pooled_kernel(
    const float* __restrict__ ctx_sum, const float* __restrict__ Wout,
    const float* __restrict__ bout, float* __restrict__ out) {
  const int b = blockIdx.x;
  const int o = threadIdx.x;
  __shared__ float mc[DD];
  mc[o] = ctx_sum[b * DD + o] * (1.f / 1024.f);
  __syncthreads();
  float acc = bout[o];
  const float* wr = Wout + (size_t)o * DD;
#pragma unroll 4
  for (int d = 0; d < DD; ++d) acc += mc[d] * wr[d];
  out[b * DD + o] = acc;
}

// ---------------------------------------------------------------------------
extern "C" void kernel_launch(void* const* d_in, const int* in_sizes, int n_in,
                              void* d_out, int out_size, void* d_ws, size_t ws_size,
                              hipStream_t stream) {
  const float* x = (const float*)d_in[0];
  const float* conv_w = (const float*)d_in[1];
  const float* emb = (const float*)d_in[2];
  const float* ipw = (const float*)d_in[3];
  const float* ipb = (const float*)d_in[4];
  const float* opw = (const float*)d_in[5];
  const float* opb = (const float*)d_in[6];

  float* out = (float*)d_out;
  float* out_pooled = out;                          // 32*256       = 8192
  float* out_sw = out + 8192;                       // 32*32*32*128 = 4194304
  float* out_topi = out + 8192 + 4194304;           // 32*32*32*8   = 262144

  // workspace layout (~99 MiB)
  char* ws = (char*)d_ws;
  float*    A      = (float*)(ws);                      // 16777216 B
  unsigned* ghist1 = (unsigned*)(ws + 16777216);        // 262144 B
  unsigned* ghist2 = (unsigned*)(ws + 17039360);        // 262144 B
  unsigned* ghist3 = (unsigned*)(ws + 17301504);        // 131072 B
  unsigned* selv   = (unsigned*)(ws + 17432576);        // 128 B
  unsigned* selr   = (unsigned*)(ws + 17432704);        // 128 B
  float*    thresh = (float*)(ws + 17432832);           // 128 B
  unsigned* gmaxb  = (unsigned*)(ws + 17432960);        // 128 B
  int*      kidx   = (int*)(ws + 17433088);             // 1048576 B
  float*    kval   = (float*)(ws + 18481664);           // 1048576 B
  unsigned short* LE  = (unsigned short*)(ws + 19530240);   // 16777216 B
  unsigned short* QKV = (unsigned short*)(ws + 36307456);   // 50331648 B
  float*    ctx    = (float*)(ws + 86639104);           // 32768 B
  unsigned short* WB  = (unsigned short*)(ws + 86671872);   // 393216 B
  unsigned short* VT  = (unsigned short*)(ws + 87065088);   // 16777216 B

  hipMemsetAsync(out_sw, 0, (size_t)4194304 * 4, stream);
  hipMemsetAsync(ws + 16777216, 0, 655872, stream);     // hists + sel + gmax
  hipMemsetAsync(ctx, 0, (size_t)BB * DD * 4, stream);

  conv_relu_hist_kernel<<<BB * C1, 256, 0, stream>>>(x, conv_w, A, ghist1, gmaxb);
  sel_kernel<<<BB, 1024, 0, stream>>>(ghist1, selv, selr, thresh, 2048, 0);
  hist2_kernel<<<dim3(16, BB), 256, 0, stream>>>(A, selv, ghist2);
  sel_kernel<<<BB, 1024, 0, stream>>>(ghist2, selv, selr, thresh, 2048, 1);
  hist3_kernel<<<dim3(16, BB), 256, 0, stream>>>(A, selv, ghist3);
  sel_kernel<<<BB, 1024, 0, stream>>>(ghist3, selv, selr, thresh, 1024, 2);
  topk_pixel_kernel<<<BB * 4, 256, 0, stream>>>(A, thresh, (const float*)gmaxb, out_sw, out_topi, kidx, kval);
  loc_emb_kernel<<<BB * SS, 256, 0, stream>>>(kidx, kval, emb, LE);
  w2bf_kernel<<<TRIPLE, 256, 0, stream>>>(ipw, WB);
  qkv_mfma_kernel<<<(BB * SS / 128) * (TRIPLE / 128), 256, 0, stream>>>(LE, WB, ipb, QKV);
  vtrans_kernel<<<BB * NHH, 256, 0, stream>>>(QKV, VT);
  attn_mfma_kernel<<<BB * NHH * (SS / 64), 256, 0, stream>>>(QKV, VT, ctx);
  pooled_kernel<<<BB, 256, 0, stream>>>(ctx, opw, opb, out_pooled);
}

// Round 6
// 320.828 us; speedup vs baseline: 1.7482x; 1.7482x over previous
//
#include <hip/hip_runtime.h>
#include <hip/hip_bf16.h>

// Problem constants
#define BB 32
#define C1 128
#define SS 1024        // H*W
#define DD 256
#define NHH 8
#define DHH 32
#define KSEL 66        // ceil(0.0005*128*32*32)
#define TRIPLE 768
#define SELFLAG 0x40000000u

typedef __attribute__((ext_vector_type(8))) short bf16x8;
typedef __attribute__((ext_vector_type(4))) short bf16x4;
typedef __attribute__((ext_vector_type(4))) float f32x4;

__device__ inline short f2bf(float f) {
  union { __hip_bfloat16 h; unsigned short u; } c;
  c.h = __float2bfloat16(f);
  return (short)c.u;
}
__device__ inline float bf2f(short s) {
  union { float f; unsigned u; } c;
  c.u = ((unsigned)(unsigned short)s) << 16;
  return c.f;
}
// pack bf16(lo),bf16(hi) into one dword via byte-perm (RTZ truncation)
__device__ inline unsigned pk2(float hi, float lo) {
  return __builtin_amdgcn_perm(__float_as_uint(hi), __float_as_uint(lo), 0x07060302u);
}

// ---------------------------------------------------------------------------
// Kernel 1: 9x9 conv (cross-correlation, pad 4) + ReLU + fused level-1
// radix histogram (top 11 bits, zeros skipped) + per-batch max.
// ---------------------------------------------------------------------------
__global__ __launch_bounds__(256) void conv_relu_hist_kernel(
    const float* __restrict__ x, const float* __restrict__ w, float* __restrict__ A,
    unsigned* __restrict__ ghist1, unsigned* __restrict__ gmaxb) {
  const int bx = blockIdx.x;              // b*128 + c
  const int b = bx >> 7, c = bx & 127;
  __shared__ float xs[40 * 40];
  __shared__ float ws[81];
  __shared__ unsigned h[2048];
  __shared__ unsigned smax;
  const int t = threadIdx.x;
  for (int i = t; i < 1600; i += 256) {
    int r = i / 40, cc = i - r * 40;
    int gi = r - 4, gj = cc - 4;
    float v = 0.f;
    if (gi >= 0 && gi < 32 && gj >= 0 && gj < 32) v = x[(size_t)b * 1024 + gi * 32 + gj];
    xs[i] = v;
  }
  if (t < 81) ws[t] = w[(size_t)c * 81 + t];
  for (int i = t; i < 2048; i += 256) h[i] = 0u;
  if (t == 0) smax = 0u;
  __syncthreads();
  unsigned lmax = 0u;
#pragma unroll
  for (int i = 0; i < 4; ++i) {
    int p = t + i * 256;
    int r = p >> 5, col = p & 31;
    float acc = 0.f;
#pragma unroll
    for (int u = 0; u < 9; ++u)
#pragma unroll
      for (int v = 0; v < 9; ++v)
        acc += xs[(r + u) * 40 + col + v] * ws[u * 9 + v];
    acc = fmaxf(acc, 0.f);
    A[(size_t)bx * 1024 + p] = acc;
    unsigned bits = __float_as_uint(acc);
    if (bits > lmax) lmax = bits;
    if (bits >= (1u << 21)) atomicAdd(&h[bits >> 21], 1u);
  }
  atomicMax(&smax, lmax);
  __syncthreads();
  for (int i = t; i < 2048; i += 256)
    if (h[i]) atomicAdd(&ghist1[b * 2048 + i], h[i]);
  if (t == 0) atomicMax(&gmaxb[b], smax);
}

// ---------------------------------------------------------------------------
// Kernel 2a/2b: level-2 / level-3 radix histograms (rare-match passes)
// ---------------------------------------------------------------------------
__global__ __launch_bounds__(256) void hist2_kernel(
    const float* __restrict__ A, const unsigned* __restrict__ selv,
    unsigned* __restrict__ gh) {
  const int b = blockIdx.y, slice = blockIdx.x, t = threadIdx.x;
  const unsigned v1 = selv[b];
  __shared__ unsigned h[2048];
  for (int i = t; i < 2048; i += 256) h[i] = 0u;
  __syncthreads();
  const float* Ab = A + (size_t)b * (C1 * SS) + slice * 8192;
#pragma unroll 4
  for (int k = 0; k < 32; ++k) {
    unsigned bits = __float_as_uint(Ab[t + k * 256]);
    if ((bits >> 21) == v1) atomicAdd(&h[(bits >> 10) & 0x7FFu], 1u);
  }
  __syncthreads();
  for (int i = t; i < 2048; i += 256)
    if (h[i]) atomicAdd(&gh[b * 2048 + i], h[i]);
}

__global__ __launch_bounds__(256) void hist3_kernel(
    const float* __restrict__ A, const unsigned* __restrict__ selv,
    unsigned* __restrict__ gh) {
  const int b = blockIdx.y, slice = blockIdx.x, t = threadIdx.x;
  const unsigned pref = selv[b];
  __shared__ unsigned h[1024];
  for (int i = t; i < 1024; i += 256) h[i] = 0u;
  __syncthreads();
  const float* Ab = A + (size_t)b * (C1 * SS) + slice * 8192;
#pragma unroll 4
  for (int k = 0; k < 32; ++k) {
    unsigned bits = __float_as_uint(Ab[t + k * 256]);
    if ((bits >> 10) == pref) atomicAdd(&h[bits & 0x3FFu], 1u);
  }
  __syncthreads();
  for (int i = t; i < 1024; i += 256)
    if (h[i]) atomicAdd(&gh[b * 1024 + i], h[i]);
}

// ---------------------------------------------------------------------------
// Kernel 3: radix-level selection via parallel suffix scan. One block / batch.
// ---------------------------------------------------------------------------
__global__ __launch_bounds__(1024) void sel_kernel(
    const unsigned* __restrict__ gh, unsigned* __restrict__ selv,
    unsigned* __restrict__ selr, float* __restrict__ thresh,
    int nbins, int stage) {
  const int b = blockIdx.x, t = threadIdx.x;
  __shared__ unsigned hl[2048];
  __shared__ unsigned sfx[1024];
  unsigned r = (stage == 0) ? (unsigned)KSEL : selr[b];
  unsigned vold = (stage == 0) ? 0u : selv[b];
  if (nbins == 2048) {
    hl[t] = gh[b * 2048 + t];
    hl[t + 1024] = gh[b * 2048 + t + 1024];
  } else {
    hl[t] = gh[b * 1024 + t];
  }
  __syncthreads();
  sfx[t] = (nbins == 2048) ? (hl[2 * t] + hl[2 * t + 1]) : hl[t];
  __syncthreads();
  for (int off = 1; off < 1024; off <<= 1) {
    unsigned v = (t + off < 1024) ? sfx[t + off] : 0u;
    __syncthreads();
    sfx[t] += v;
    __syncthreads();
  }
  if ((stage != 0 && vold == SELFLAG) || sfx[0] < r) {
    if (t == 0) {
      if (stage == 2) thresh[b] = 0.0f;
      else { selv[b] = SELFLAG; selr[b] = r; }
    }
    return;
  }
  unsigned Snext = (t < 1023) ? sfx[t + 1] : 0u;
  if (nbins == 2048) {
    unsigned hi = hl[2 * t + 1], lo = hl[2 * t];
    if (Snext < r && Snext + hi >= r) {
      selv[b] = (vold << 11) | (unsigned)(2 * t + 1);
      selr[b] = r - Snext;
    } else if (Snext + hi < r && Snext + hi + lo >= r) {
      selv[b] = (vold << 11) | (unsigned)(2 * t);
      selr[b] = r - Snext - hi;
    }
  } else {
    if (Snext < r && sfx[t] >= r)
      thresh[b] = __uint_as_float((vold << 10) | (unsigned)t);
  }
}

// ---------------------------------------------------------------------------
// Kernel 4: per-pixel masked channel top-8 (jax tie-break semantics).
// ---------------------------------------------------------------------------
__global__ __launch_bounds__(256) void topk_pixel_kernel(
    const float* __restrict__ A, const float* __restrict__ thresh,
    const float* __restrict__ gmaxp, float* __restrict__ out_sw,
    float* __restrict__ out_topi, int* __restrict__ kidx, float* __restrict__ kval) {
  const int bx = blockIdx.x;              // b*4 + chunk
  const int b = bx >> 2;
  const int p = ((bx & 3) << 8) + threadIdx.x;
  const float th = thresh[b];
  const float gm = gmaxp[b];
  const float scale = gm > 0.f ? 1.f / gm : 0.f;
  const float* Ab = A + (size_t)b * (C1 * SS) + p;

  float tv0 = -1.f, tv1 = -1.f, tv2 = -1.f, tv3 = -1.f, tv4 = -1.f, tv5 = -1.f, tv6 = -1.f, tv7 = -1.f;
  int ti0 = 0, ti1 = 0, ti2 = 0, ti3 = 0, ti4 = 0, ti5 = 0, ti6 = 0, ti7 = 0;
  int cnt = 0;
#pragma unroll 1
  for (int c = 0; c < C1; ++c) {
    float v = Ab[(size_t)c << 10];
    if (v >= th) {
      ++cnt;
      bool s7 = v > tv6, p7 = (v > tv7) && !s7;
      float n7 = p7 ? v : (s7 ? tv6 : tv7); int m7 = p7 ? c : (s7 ? ti6 : ti7);
      bool s6 = v > tv5, p6 = (v > tv6) && !s6;
      float n6 = p6 ? v : (s6 ? tv5 : tv6); int m6 = p6 ? c : (s6 ? ti5 : ti6);
      bool s5 = v > tv4, p5 = (v > tv5) && !s5;
      float n5 = p5 ? v : (s5 ? tv4 : tv5); int m5 = p5 ? c : (s5 ? ti4 : ti5);
      bool s4 = v > tv3, p4 = (v > tv4) && !s4;
      float n4 = p4 ? v : (s4 ? tv3 : tv4); int m4 = p4 ? c : (s4 ? ti3 : ti4);
      bool s3 = v > tv2, p3 = (v > tv3) && !s3;
      float n3 = p3 ? v : (s3 ? tv2 : tv3); int m3 = p3 ? c : (s3 ? ti2 : ti3);
      bool s2 = v > tv1, p2 = (v > tv2) && !s2;
      float n2 = p2 ? v : (s2 ? tv1 : tv2); int m2 = p2 ? c : (s2 ? ti1 : ti2);
      bool s1 = v > tv0, p1 = (v > tv1) && !s1;
      float n1 = p1 ? v : (s1 ? tv0 : tv1); int m1 = p1 ? c : (s1 ? ti0 : ti1);
      bool p0 = v > tv0;
      float n0 = p0 ? v : tv0; int m0 = p0 ? c : ti0;
      tv7 = n7; ti7 = m7; tv6 = n6; ti6 = m6; tv5 = n5; ti5 = m5; tv4 = n4; ti4 = m4;
      tv3 = n3; ti3 = m3; tv2 = n2; ti2 = m2; tv1 = n1; ti1 = m1; tv0 = n0; ti0 = m0;
    }
  }
  const int m = cnt < 8 ? cnt : 8;
  int fv[8] = {ti0, ti1, ti2, ti3, ti4, ti5, ti6, ti7};
  int fill_c = 0;
#pragma unroll
  for (int j = 0; j < 8; ++j) {
    if (j >= m) {
      bool adv = true;
      while (adv) {
        adv = false;
#pragma unroll
        for (int t2 = 0; t2 < 8; ++t2)
          if (t2 < m && fv[t2] == fill_c) adv = true;
        if (adv) ++fill_c;
      }
      fv[j] = fill_c;
      ++fill_c;
    }
  }
  ti0 = fv[0]; ti1 = fv[1]; ti2 = fv[2]; ti3 = fv[3]; ti4 = fv[4]; ti5 = fv[5]; ti6 = fv[6]; ti7 = fv[7];
  if (m <= 0) tv0 = 0.f; if (m <= 1) tv1 = 0.f; if (m <= 2) tv2 = 0.f; if (m <= 3) tv3 = 0.f;
  if (m <= 4) tv4 = 0.f; if (m <= 5) tv5 = 0.f; if (m <= 6) tv6 = 0.f; if (m <= 7) tv7 = 0.f;

  const size_t pix = (size_t)b * SS + p;
  float* tp = out_topi + pix * 8;
  tp[0] = (float)ti0; tp[1] = (float)ti1; tp[2] = (float)ti2; tp[3] = (float)ti3;
  tp[4] = (float)ti4; tp[5] = (float)ti5; tp[6] = (float)ti6; tp[7] = (float)ti7;
  int* ki = kidx + pix * 8;
  ki[0] = ti0; ki[1] = ti1; ki[2] = ti2; ki[3] = ti3; ki[4] = ti4; ki[5] = ti5; ki[6] = ti6; ki[7] = ti7;
  float* kv = kval + pix * 8;
  float sv0 = tv0 * scale, sv1 = tv1 * scale, sv2 = tv2 * scale, sv3 = tv3 * scale;
  float sv4 = tv4 * scale, sv5 = tv5 * scale, sv6 = tv6 * scale, sv7 = tv7 * scale;
  kv[0] = sv0; kv[1] = sv1; kv[2] = sv2; kv[3] = sv3; kv[4] = sv4; kv[5] = sv5; kv[6] = sv6; kv[7] = sv7;
  float* sw = out_sw + pix * C1;
  if (m > 0) sw[ti0] = sv0; if (m > 1) sw[ti1] = sv1; if (m > 2) sw[ti2] = sv2; if (m > 3) sw[ti3] = sv3;
  if (m > 4) sw[ti4] = sv4; if (m > 5) sw[ti5] = sv5; if (m > 6) sw[ti6] = sv6; if (m > 7) sw[ti7] = sv7;
}

// ---------------------------------------------------------------------------
// Kernel 5: loc_emb(b,p,d) = PE(w,d) + sum_j kval[j]*emb[kidx[j], d] -> bf16
// ---------------------------------------------------------------------------
__global__ __launch_bounds__(256) void loc_emb_kernel(
    const int* __restrict__ kidx, const float* __restrict__ kval,
    const float* __restrict__ emb, unsigned short* __restrict__ le) {
  const int pix = blockIdx.x;             // b*1024 + p
  const int d = threadIdx.x;
  const int w = pix & 31;
  const int i2 = d >> 1;
  const float div = expf((float)(2 * i2) * (-9.210340371976184f / 256.f));
  const float ang = (float)w * div;
  const float pe = (d & 1) ? cosf(ang) : sinf(ang);
  const int* ki = kidx + (size_t)pix * 8;
  const float* kv = kval + (size_t)pix * 8;
  float acc = pe;
#pragma unroll
  for (int j = 0; j < 8; ++j) acc += kv[j] * emb[(size_t)ki[j] * DD + d];
  le[(size_t)pix * DD + d] = (unsigned short)f2bf(acc);
}

// ---------------------------------------------------------------------------
// Kernel 5b: in_proj_w fp32 -> bf16
// ---------------------------------------------------------------------------
__global__ __launch_bounds__(256) void w2bf_kernel(
    const float* __restrict__ W, unsigned short* __restrict__ Wb) {
  int i = blockIdx.x * 256 + threadIdx.x;
  Wb[i] = (unsigned short)f2bf(W[i]);
}

// ---------------------------------------------------------------------------
// Kernel 6: QKV(bf16) = LE @ Wb^T + bias.  128x128 tile, 2x2 waves, K-step 32.
// ---------------------------------------------------------------------------
__global__ __launch_bounds__(256) void qkv_mfma_kernel(
    const unsigned short* __restrict__ Xb, const unsigned short* __restrict__ Wb,
    const float* __restrict__ bias, unsigned short* __restrict__ Yb) {
  __shared__ __align__(16) short As[128][40];
  __shared__ __align__(16) short Bs[128][40];
  const int bid = blockIdx.x;                 // 1536 blocks = 8 * 192
  const int wgid = (bid & 7) * 192 + (bid >> 3);
  const int nt = wgid % 6, mt = wgid / 6;
  const int t = threadIdx.x;
  const int wv = t >> 6, lane = t & 63, lg = lane >> 4, ln = lane & 15;
  const int wm = wv >> 1, wn = wv & 1;

  const int srow = t & 127;
  const int sc0 = (t >> 7) * 8, sc1 = sc0 + 16;
  const unsigned short* xr = Xb + (size_t)(mt * 128 + srow) * DD;
  const unsigned short* wr = Wb + (size_t)(nt * 128 + srow) * DD;

  f32x4 acc[4][4];
#pragma unroll
  for (int i = 0; i < 4; ++i)
#pragma unroll
    for (int j = 0; j < 4; ++j) acc[i][j] = (f32x4){0, 0, 0, 0};

  bf16x8 xa0 = *(const bf16x8*)&xr[sc0];
  bf16x8 xa1 = *(const bf16x8*)&xr[sc1];
  bf16x8 wa0 = *(const bf16x8*)&wr[sc0];
  bf16x8 wa1 = *(const bf16x8*)&wr[sc1];

  for (int k0 = 0; k0 < DD; k0 += 32) {
    __syncthreads();
    *(bf16x8*)&As[srow][sc0] = xa0;
    *(bf16x8*)&As[srow][sc1] = xa1;
    *(bf16x8*)&Bs[srow][sc0] = wa0;
    *(bf16x8*)&Bs[srow][sc1] = wa1;
    if (k0 + 32 < DD) {
      xa0 = *(const bf16x8*)&xr[k0 + 32 + sc0];
      xa1 = *(const bf16x8*)&xr[k0 + 32 + sc1];
      wa0 = *(const bf16x8*)&wr[k0 + 32 + sc0];
      wa1 = *(const bf16x8*)&wr[k0 + 32 + sc1];
    }
    __syncthreads();
    bf16x8 af[4], bfr[4];
#pragma unroll
    for (int i = 0; i < 4; ++i) af[i] = *(const bf16x8*)&As[wm * 64 + i * 16 + ln][lg * 8];
#pragma unroll
    for (int j = 0; j < 4; ++j) bfr[j] = *(const bf16x8*)&Bs[wn * 64 + j * 16 + ln][lg * 8];
#pragma unroll
    for (int i = 0; i < 4; ++i)
#pragma unroll
      for (int j = 0; j < 4; ++j)
        acc[i][j] = __builtin_amdgcn_mfma_f32_16x16x32_bf16(af[i], bfr[j], acc[i][j], 0, 0, 0);
  }
#pragma unroll
  for (int i = 0; i < 4; ++i) {
#pragma unroll
    for (int j = 0; j < 4; ++j) {
      int col = nt * 128 + wn * 64 + j * 16 + ln;
      float bcol = bias[col];
#pragma unroll
      for (int r = 0; r < 4; ++r) {
        int row = mt * 128 + wm * 64 + i * 16 + lg * 4 + r;
        Yb[(size_t)row * TRIPLE + col] = (unsigned short)f2bf(acc[i][j][r] + bcol);
      }
    }
  }
}

// ---------------------------------------------------------------------------
// Kernel 6b: V-transpose.  VT[(b*8+h)*32 + d][seq] = QKV[b][seq][512+h*32+d]
// ---------------------------------------------------------------------------
__global__ __launch_bounds__(256) void vtrans_kernel(
    const unsigned short* __restrict__ QKV, unsigned short* __restrict__ VT) {
  const int bh = blockIdx.x;           // b*8+h
  const int b = bh >> 3, h = bh & 7;
  const int t = threadIdx.x;
  __shared__ __align__(16) short Ls[32][136];
  const unsigned short* src0 = QKV + (size_t)b * SS * TRIPLE + 2 * DD + h * DHH;
  for (int chunk = 0; chunk < 8; ++chunk) {
    if (chunk) __syncthreads();
#pragma unroll
    for (int u = 0; u < 2; ++u) {
      int unit = t + u * 256;          // 0..511
      int key = unit & 127, dg = unit >> 7;
      bf16x8 v = *(const bf16x8*)(src0 + (size_t)(chunk * 128 + key) * TRIPLE + dg * 8);
#pragma unroll
      for (int j = 0; j < 8; ++j) Ls[dg * 8 + j][key] = v[j];
    }
    __syncthreads();
#pragma unroll
    for (int u = 0; u < 2; ++u) {
      int unit = t + u * 256;
      int d = unit >> 4, sc = unit & 15;
      bf16x8 v = *(const bf16x8*)&Ls[d][sc * 8];
      *(bf16x8*)(VT + ((size_t)bh * DHH + d) * SS + chunk * 128 + sc * 8) = v;
    }
  }
}

// ---------------------------------------------------------------------------
// Kernel 7: hybrid bf16 MFMA flash attention.
// K & V^T cooperatively staged in LDS (coalesced b128 writes, reg prefetch);
// double-swapped MFMA: QK^T = mfma32(K,Q) -> P lane-local; PV = mfma16(V^T,P)
// with P straight from registers (no LDS round-trip, lane-local softmax).
// Block = (b, h, 128-q-chunk); 4 waves x 2 q-sets x 16 q.  2048 blocks.
// ---------------------------------------------------------------------------
__global__ __launch_bounds__(256) void attn_mfma_kernel(
    const unsigned short* __restrict__ QKV, const unsigned short* __restrict__ VT,
    float* __restrict__ ctx_sum) {
  const int bid = blockIdx.x;                 // 2048 blocks = 8 * 256
  const int wgid = (bid & 7) * 256 + (bid >> 3);
  const int qc = wgid & 7;
  const int h = (wgid >> 3) & 7;
  const int b = wgid >> 6;
  const int t = threadIdx.x;
  const int wv = t >> 6, lane = t & 63, lg = lane >> 4, ln = lane & 15;

  __shared__ __align__(16) short Ks[64][40];   // K tile [key][dh]
  __shared__ __align__(16) short Vt[32][72];   // V^T tile [dh][key]

  const size_t baseB = (size_t)b * SS * TRIPLE;
  const float qsc = 0.25506973f;              // (1/sqrt(32)) * log2(e)

  // Q B-operands (two q-sets): col = ln (q), k = lg*8+j (d); exp2-domain scale
  bf16x8 qf0, qf1;
  {
    const unsigned short* qp0 = QKV + baseB + (size_t)(qc * 128 + wv * 16 + ln) * TRIPLE + h * DHH + lg * 8;
    bf16x8 qr0 = *(const bf16x8*)qp0;
    bf16x8 qr1 = *(const bf16x8*)(qp0 + (size_t)64 * TRIPLE);
#pragma unroll
    for (int j = 0; j < 8; ++j) {
      qf0[j] = f2bf(bf2f(qr0[j]) * qsc);
      qf1[j] = f2bf(bf2f(qr1[j]) * qsc);
    }
  }
  // staging maps (coalesced global, b128 LDS writes)
  const int keyK = (t & 15) | ((t >> 6) << 4);     // 64 keys x 4 d-chunks
  const int d0K = ((t >> 4) & 3) * 8;
  const int dV = t >> 3;                            // 32 d x 8 key-chunks
  const int kcV = t & 7;
  const unsigned short* kgp = QKV + baseB + DD + h * DHH + (size_t)keyK * TRIPLE + d0K;
  const unsigned short* vgp = VT + ((size_t)(b * NHH + h) * DHH + dV) * SS + kcV * 8;

  float m0 = -1e30f, l0 = 0.f, m1 = -1e30f, l1 = 0.f;
  f32x4 acc00 = {0, 0, 0, 0}, acc01 = {0, 0, 0, 0};  // q-set0: d 0-15, 16-31
  f32x4 acc10 = {0, 0, 0, 0}, acc11 = {0, 0, 0, 0};  // q-set1

  bf16x8 kreg = *(const bf16x8*)kgp;
  bf16x8 vreg = *(const bf16x8*)vgp;

#pragma unroll 1
  for (int tile = 0; tile < 16; ++tile) {
    __syncthreads();
    *(bf16x8*)&Ks[keyK][d0K] = kreg;
    *(bf16x8*)&Vt[dV][kcV * 8] = vreg;
    if (tile < 15) {
      kreg = *(const bf16x8*)(kgp + (size_t)(tile + 1) * 64 * TRIPLE);
      vreg = *(const bf16x8*)(vgp + (tile + 1) * 64);
    }
    __syncthreads();

    // QK^T for both q-sets; lane ln = q, (lg, r) spans 16 keys per st
    bf16x8 ka0 = *(const bf16x8*)&Ks[0 * 16 + ln][lg * 8];
    bf16x8 ka1 = *(const bf16x8*)&Ks[1 * 16 + ln][lg * 8];
    bf16x8 ka2 = *(const bf16x8*)&Ks[2 * 16 + ln][lg * 8];
    bf16x8 ka3 = *(const bf16x8*)&Ks[3 * 16 + ln][lg * 8];
    f32x4 s0 = __builtin_amdgcn_mfma_f32_16x16x32_bf16(ka0, qf0, (f32x4){0, 0, 0, 0}, 0, 0, 0);
    f32x4 s1 = __builtin_amdgcn_mfma_f32_16x16x32_bf16(ka1, qf0, (f32x4){0, 0, 0, 0}, 0, 0, 0);
    f32x4 s2 = __builtin_amdgcn_mfma_f32_16x16x32_bf16(ka2, qf0, (f32x4){0, 0, 0, 0}, 0, 0, 0);
    f32x4 s3 = __builtin_amdgcn_mfma_f32_16x16x32_bf16(ka3, qf0, (f32x4){0, 0, 0, 0}, 0, 0, 0);
    f32x4 u0 = __builtin_amdgcn_mfma_f32_16x16x32_bf16(ka0, qf1, (f32x4){0, 0, 0, 0}, 0, 0, 0);
    f32x4 u1 = __builtin_amdgcn_mfma_f32_16x16x32_bf16(ka1, qf1, (f32x4){0, 0, 0, 0}, 0, 0, 0);
    f32x4 u2 = __builtin_amdgcn_mfma_f32_16x16x32_bf16(ka2, qf1, (f32x4){0, 0, 0, 0}, 0, 0, 0);
    f32x4 u3 = __builtin_amdgcn_mfma_f32_16x16x32_bf16(ka3, qf1, (f32x4){0, 0, 0, 0}, 0, 0, 0);

    // V^T fragments (shared by both q-sets)
    bf16x4 va00 = *(const bf16x4*)&Vt[0 + ln][0 + lg * 4];
    bf16x4 va01 = *(const bf16x4*)&Vt[0 + ln][16 + lg * 4];
    bf16x4 va02 = *(const bf16x4*)&Vt[0 + ln][32 + lg * 4];
    bf16x4 va03 = *(const bf16x4*)&Vt[0 + ln][48 + lg * 4];
    bf16x4 va10 = *(const bf16x4*)&Vt[16 + ln][0 + lg * 4];
    bf16x4 va11 = *(const bf16x4*)&Vt[16 + ln][16 + lg * 4];
    bf16x4 va12 = *(const bf16x4*)&Vt[16 + ln][32 + lg * 4];
    bf16x4 va13 = *(const bf16x4*)&Vt[16 + ln][48 + lg * 4];

    // ---- lane-local online softmax, q-set 0 (exp2 domain) ----
    {
      float mx = fmaxf(fmaxf(fmaxf(s0[0], s0[1]), fmaxf(s0[2], s0[3])),
                       fmaxf(fmaxf(s1[0], s1[1]), fmaxf(s1[2], s1[3])));
      mx = fmaxf(mx, fmaxf(fmaxf(fmaxf(s2[0], s2[1]), fmaxf(s2[2], s2[3])),
                           fmaxf(fmaxf(s3[0], s3[1]), fmaxf(s3[2], s3[3]))));
      mx = fmaxf(mx, __shfl_xor(mx, 16));
      mx = fmaxf(mx, __shfl_xor(mx, 32));
      float mn = fmaxf(m0, mx);
      float corr = exp2f(m0 - mn);
      m0 = mn;
      float ps = 0.f;
#pragma unroll
      for (int r = 0; r < 4; ++r) { s0[r] = exp2f(s0[r] - mn); ps += s0[r]; }
#pragma unroll
      for (int r = 0; r < 4; ++r) { s1[r] = exp2f(s1[r] - mn); ps += s1[r]; }
#pragma unroll
      for (int r = 0; r < 4; ++r) { s2[r] = exp2f(s2[r] - mn); ps += s2[r]; }
#pragma unroll
      for (int r = 0; r < 4; ++r) { s3[r] = exp2f(s3[r] - mn); ps += s3[r]; }
      ps += __shfl_xor(ps, 16);
      ps += __shfl_xor(ps, 32);
      l0 = l0 * corr + ps;
      union { bf16x4 v; unsigned u[2]; } pb0, pb1, pb2, pb3;
      pb0.u[0] = pk2(s0[1], s0[0]); pb0.u[1] = pk2(s0[3], s0[2]);
      pb1.u[0] = pk2(s1[1], s1[0]); pb1.u[1] = pk2(s1[3], s1[2]);
      pb2.u[0] = pk2(s2[1], s2[0]); pb2.u[1] = pk2(s2[3], s2[2]);
      pb3.u[0] = pk2(s3[1], s3[0]); pb3.u[1] = pk2(s3[3], s3[2]);
      acc00 *= corr;
      acc01 *= corr;
      acc00 = __builtin_amdgcn_mfma_f32_16x16x16bf16_1k(va00, pb0.v, acc00, 0, 0, 0);
      acc00 = __builtin_amdgcn_mfma_f32_16x16x16bf16_1k(va01, pb1.v, acc00, 0, 0, 0);
      acc00 = __builtin_amdgcn_mfma_f32_16x16x16bf16_1k(va02, pb2.v, acc00, 0, 0, 0);
      acc00 = __builtin_amdgcn_mfma_f32_16x16x16bf16_1k(va03, pb3.v, acc00, 0, 0, 0);
      acc01 = __builtin_amdgcn_mfma_f32_16x16x16bf16_1k(va10, pb0.v, acc01, 0, 0, 0);
      acc01 = __builtin_amdgcn_mfma_f32_16x16x16bf16_1k(va11, pb1.v, acc01, 0, 0, 0);
      acc01 = __builtin_amdgcn_mfma_f32_16x16x16bf16_1k(va12, pb2.v, acc01, 0, 0, 0);
      acc01 = __builtin_amdgcn_mfma_f32_16x16x16bf16_1k(va13, pb3.v, acc01, 0, 0, 0);
    }
    // ---- lane-local online softmax, q-set 1 ----
    {
      float mx = fmaxf(fmaxf(fmaxf(u0[0], u0[1]), fmaxf(u0[2], u0[3])),
                       fmaxf(fmaxf(u1[0], u1[1]), fmaxf(u1[2], u1[3])));
      mx = fmaxf(mx, fmaxf(fmaxf(fmaxf(u2[0], u2[1]), fmaxf(u2[2], u2[3])),
                           fmaxf(fmaxf(u3[0], u3[1]), fmaxf(u3[2], u3[3]))));
      mx = fmaxf(mx, __shfl_xor(mx, 16));
      mx = fmaxf(mx, __shfl_xor(mx, 32));
      float mn = fmaxf(m1, mx);
      float corr = exp2f(m1 - mn);
      m1 = mn;
      float ps = 0.f;
#pragma unroll
      for (int r = 0; r < 4; ++r) { u0[r] = exp2f(u0[r] - mn); ps += u0[r]; }
#pragma unroll
      for (int r = 0; r < 4; ++r) { u1[r] = exp2f(u1[r] - mn); ps += u1[r]; }
#pragma unroll
      for (int r = 0; r < 4; ++r) { u2[r] = exp2f(u2[r] - mn); ps += u2[r]; }
#pragma unroll
      for (int r = 0; r < 4; ++r) { u3[r] = exp2f(u3[r] - mn); ps += u3[r]; }
      ps += __shfl_xor(ps, 16);
      ps += __shfl_xor(ps, 32);
      l1 = l1 * corr + ps;
      union { bf16x4 v; unsigned u[2]; } pb0, pb1, pb2, pb3;
      pb0.u[0] = pk2(u0[1], u0[0]); pb0.u[1] = pk2(u0[3], u0[2]);
      pb1.u[0] = pk2(u1[1], u1[0]); pb1.u[1] = pk2(u1[3], u1[2]);
      pb2.u[0] = pk2(u2[1], u2[0]); pb2.u[1] = pk2(u2[3], u2[2]);
      pb3.u[0] = pk2(u3[1], u3[0]); pb3.u[1] = pk2(u3[3], u3[2]);
      acc10 *= corr;
      acc11 *= corr;
      acc10 = __builtin_amdgcn_mfma_f32_16x16x16bf16_1k(va00, pb0.v, acc10, 0, 0, 0);
      acc10 = __builtin_amdgcn_mfma_f32_16x16x16bf16_1k(va01, pb1.v, acc10, 0, 0, 0);
      acc10 = __builtin_amdgcn_mfma_f32_16x16x16bf16_1k(va02, pb2.v, acc10, 0, 0, 0);
      acc10 = __builtin_amdgcn_mfma_f32_16x16x16bf16_1k(va03, pb3.v, acc10, 0, 0, 0);
      acc11 = __builtin_amdgcn_mfma_f32_16x16x16bf16_1k(va10, pb0.v, acc11, 0, 0, 0);
      acc11 = __builtin_amdgcn_mfma_f32_16x16x16bf16_1k(va11, pb1.v, acc11, 0, 0, 0);
      acc11 = __builtin_amdgcn_mfma_f32_16x16x16bf16_1k(va12, pb2.v, acc11, 0, 0, 0);
      acc11 = __builtin_amdgcn_mfma_f32_16x16x16bf16_1k(va13, pb3.v, acc11, 0, 0, 0);
    }
  }

  // normalize (lane-local q), combine both q-sets, reduce over 16 q, atomic
  float invl0 = 1.f / l0, invl1 = 1.f / l1;
  float* cbase = &ctx_sum[b * DD + h * DHH];
#pragma unroll
  for (int r = 0; r < 4; ++r) {
    float v0 = acc00[r] * invl0 + acc10[r] * invl1;
    v0 += __shfl_xor(v0, 1); v0 += __shfl_xor(v0, 2);
    v0 += __shfl_xor(v0, 4); v0 += __shfl_xor(v0, 8);
    if (ln == 0) atomicAdd(cbase + lg * 4 + r, v0);
    float v1 = acc01[r] * invl0 + acc11[r] * invl1;
    v1 += __shfl_xor(v1, 1); v1 += __shfl_xor(v1, 2);
    v1 += __shfl_xor(v1, 4); v1 += __shfl_xor(v1, 8);
    if (ln == 0) atomicAdd(cbase + 16 + lg * 4 + r, v1);
  }
}

// ---------------------------------------------------------------------------
// Kernel 8: pooled(b,o) = bias[o] + sum_d (ctx_sum[b,d]/1024) * Wout[o,d]
// ---------------------------------------------------------------------------
__global__ __launch_bounds__(256) void pooled_kernel(
    const float* __restrict__ ctx_sum, const float* __restrict__ Wout,
    const float* __restrict__ bout, float* __restrict__ out) {
  const int b = blockIdx.x;
  const int o = threadIdx.x;
  __shared__ float mc[DD];
  mc[o] = ctx_sum[b * DD + o] * (1.f / 1024.f);
  __syncthreads();
  float acc = bout[o];
  const float* wr = Wout + (size_t)o * DD;
#pragma unroll 4
  for (int d = 0; d < DD; ++d) acc += mc[d] * wr[d];
  out[b * DD + o] = acc;
}

// ---------------------------------------------------------------------------
extern "C" void kernel_launch(void* const* d_in, const int* in_sizes, int n_in,
                              void* d_out, int out_size, void* d_ws, size_t ws_size,
                              hipStream_t stream) {
  const float* x = (const float*)d_in[0];
  const float* conv_w = (const float*)d_in[1];
  const float* emb = (const float*)d_in[2];
  const float* ipw = (const float*)d_in[3];
  const float* ipb = (const float*)d_in[4];
  const float* opw = (const float*)d_in[5];
  const float* opb = (const float*)d_in[6];

  float* out = (float*)d_out;
  float* out_pooled = out;                          // 32*256       = 8192
  float* out_sw = out + 8192;                       // 32*32*32*128 = 4194304
  float* out_topi = out + 8192 + 4194304;           // 32*32*32*8   = 262144

  // workspace layout (~99 MiB)
  char* ws = (char*)d_ws;
  float*    A      = (float*)(ws);                      // 16777216 B
  unsigned* ghist1 = (unsigned*)(ws + 16777216);        // 262144 B
  unsigned* ghist2 = (unsigned*)(ws + 17039360);        // 262144 B
  unsigned* ghist3 = (unsigned*)(ws + 17301504);        // 131072 B
  unsigned* selv   = (unsigned*)(ws + 17432576);        // 128 B
  unsigned* selr   = (unsigned*)(ws + 17432704);        // 128 B
  float*    thresh = (float*)(ws + 17432832);           // 128 B
  unsigned* gmaxb  = (unsigned*)(ws + 17432960);        // 128 B
  int*      kidx   = (int*)(ws + 17433088);             // 1048576 B
  float*    kval   = (float*)(ws + 18481664);           // 1048576 B
  unsigned short* LE  = (unsigned short*)(ws + 19530240);   // 16777216 B
  unsigned short* QKV = (unsigned short*)(ws + 36307456);   // 50331648 B
  float*    ctx    = (float*)(ws + 86639104);           // 32768 B
  unsigned short* WB  = (unsigned short*)(ws + 86671872);   // 393216 B
  unsigned short* VT  = (unsigned short*)(ws + 87065088);   // 16777216 B

  hipMemsetAsync(out_sw, 0, (size_t)4194304 * 4, stream);
  hipMemsetAsync(ws + 16777216, 0, 655872, stream);     // hists + sel + gmax
  hipMemsetAsync(ctx, 0, (size_t)BB * DD * 4, stream);

  conv_relu_hist_kernel<<<BB * C1, 256, 0, stream>>>(x, conv_w, A, ghist1, gmaxb);
  sel_kernel<<<BB, 1024, 0, stream>>>(ghist1, selv, selr, thresh, 2048, 0);
  hist2_kernel<<<dim3(16, BB), 256, 0, stream>>>(A, selv, ghist2);
  sel_kernel<<<BB, 1024, 0, stream>>>(ghist2, selv, selr, thresh, 2048, 1);
  hist3_kernel<<<dim3(16, BB), 256, 0, stream>>>(A, selv, ghist3);
  sel_kernel<<<BB, 1024, 0, stream>>>(ghist3, selv, selr, thresh, 1024, 2);
  topk_pixel_kernel<<<BB * 4, 256, 0, stream>>>(A, thresh, (const float*)gmaxb, out_sw, out_topi, kidx, kval);
  loc_emb_kernel<<<BB * SS, 256, 0, stream>>>(kidx, kval, emb, LE);
  w2bf_kernel<<<TRIPLE, 256, 0, stream>>>(ipw, WB);
  qkv_mfma_kernel<<<(BB * SS / 128) * (TRIPLE / 128), 256, 0, stream>>>(LE, WB, ipb, QKV);
  vtrans_kernel<<<BB * NHH, 256, 0, stream>>>(QKV, VT);
  attn_mfma_kernel<<<BB * NHH * (SS / 128), 256, 0, stream>>>(QKV, VT, ctx);
  pooled_kernel<<<BB, 256, 0, stream>>>(ctx, opw, opb, out_pooled);
}

// Round 7
// 247.437 us; speedup vs baseline: 2.2667x; 1.2966x over previous
//
#include <hip/hip_runtime.h>
#include <hip/hip_bf16.h>

// Problem constants
#define BB 32
#define C1 128
#define SS 1024        // H*W
#define DD 256
#define NHH 8
#define DHH 32
#define KSEL 66        // ceil(0.0005*128*32*32)
#define TRIPLE 768
#define SCAP 128       // sparse-token capacity per batch (>= 66)
#define DMAX (32 + SCAP)
#define SELFLAG 0x40000000u

typedef __attribute__((ext_vector_type(8))) short bf16x8;
typedef __attribute__((ext_vector_type(4))) float f32x4;

__device__ inline short f2bf(float f) {
  union { __hip_bfloat16 h; unsigned short u; } c;
  c.h = __float2bfloat16(f);
  return (short)c.u;
}

// ---------------------------------------------------------------------------
// Kernel 1: 9x9 conv (cross-correlation, pad 4) + ReLU + fused level-1
// radix histogram (top 11 bits, zeros skipped) + per-batch max.
// ---------------------------------------------------------------------------
__global__ __launch_bounds__(256) void conv_relu_hist_kernel(
    const float* __restrict__ x, const float* __restrict__ w, float* __restrict__ A,
    unsigned* __restrict__ ghist1, unsigned* __restrict__ gmaxb) {
  const int bx = blockIdx.x;              // b*128 + c
  const int b = bx >> 7, c = bx & 127;
  __shared__ float xs[40 * 40];
  __shared__ float ws[81];
  __shared__ unsigned h[2048];
  __shared__ unsigned smax;
  const int t = threadIdx.x;
  for (int i = t; i < 1600; i += 256) {
    int r = i / 40, cc = i - r * 40;
    int gi = r - 4, gj = cc - 4;
    float v = 0.f;
    if (gi >= 0 && gi < 32 && gj >= 0 && gj < 32) v = x[(size_t)b * 1024 + gi * 32 + gj];
    xs[i] = v;
  }
  if (t < 81) ws[t] = w[(size_t)c * 81 + t];
  for (int i = t; i < 2048; i += 256) h[i] = 0u;
  if (t == 0) smax = 0u;
  __syncthreads();
  unsigned lmax = 0u;
#pragma unroll
  for (int i = 0; i < 4; ++i) {
    int p = t + i * 256;
    int r = p >> 5, col = p & 31;
    float acc = 0.f;
#pragma unroll
    for (int u = 0; u < 9; ++u)
#pragma unroll
      for (int v = 0; v < 9; ++v)
        acc += xs[(r + u) * 40 + col + v] * ws[u * 9 + v];
    acc = fmaxf(acc, 0.f);
    A[(size_t)bx * 1024 + p] = acc;
    unsigned bits = __float_as_uint(acc);
    if (bits > lmax) lmax = bits;
    if (bits >= (1u << 21)) atomicAdd(&h[bits >> 21], 1u);
  }
  atomicMax(&smax, lmax);
  __syncthreads();
  for (int i = t; i < 2048; i += 256)
    if (h[i]) atomicAdd(&ghist1[b * 2048 + i], h[i]);
  if (t == 0) atomicMax(&gmaxb[b], smax);
}

// ---------------------------------------------------------------------------
// Kernel 2a/2b: level-2 / level-3 radix histograms (rare-match passes)
// ---------------------------------------------------------------------------
__global__ __launch_bounds__(256) void hist2_kernel(
    const float* __restrict__ A, const unsigned* __restrict__ selv,
    unsigned* __restrict__ gh) {
  const int b = blockIdx.y, slice = blockIdx.x, t = threadIdx.x;
  const unsigned v1 = selv[b];
  __shared__ unsigned h[2048];
  for (int i = t; i < 2048; i += 256) h[i] = 0u;
  __syncthreads();
  const float* Ab = A + (size_t)b * (C1 * SS) + slice * 8192;
#pragma unroll 4
  for (int k = 0; k < 32; ++k) {
    unsigned bits = __float_as_uint(Ab[t + k * 256]);
    if ((bits >> 21) == v1) atomicAdd(&h[(bits >> 10) & 0x7FFu], 1u);
  }
  __syncthreads();
  for (int i = t; i < 2048; i += 256)
    if (h[i]) atomicAdd(&gh[b * 2048 + i], h[i]);
}

__global__ __launch_bounds__(256) void hist3_kernel(
    const float* __restrict__ A, const unsigned* __restrict__ selv,
    unsigned* __restrict__ gh) {
  const int b = blockIdx.y, slice = blockIdx.x, t = threadIdx.x;
  const unsigned pref = selv[b];
  __shared__ unsigned h[1024];
  for (int i = t; i < 1024; i += 256) h[i] = 0u;
  __syncthreads();
  const float* Ab = A + (size_t)b * (C1 * SS) + slice * 8192;
#pragma unroll 4
  for (int k = 0; k < 32; ++k) {
    unsigned bits = __float_as_uint(Ab[t + k * 256]);
    if ((bits >> 10) == pref) atomicAdd(&h[bits & 0x3FFu], 1u);
  }
  __syncthreads();
  for (int i = t; i < 1024; i += 256)
    if (h[i]) atomicAdd(&gh[b * 1024 + i], h[i]);
}

// ---------------------------------------------------------------------------
// Kernel 3: radix-level selection via parallel suffix scan. One block / batch.
// ---------------------------------------------------------------------------
__global__ __launch_bounds__(1024) void sel_kernel(
    const unsigned* __restrict__ gh, unsigned* __restrict__ selv,
    unsigned* __restrict__ selr, float* __restrict__ thresh,
    int nbins, int stage) {
  const int b = blockIdx.x, t = threadIdx.x;
  __shared__ unsigned hl[2048];
  __shared__ unsigned sfx[1024];
  unsigned r = (stage == 0) ? (unsigned)KSEL : selr[b];
  unsigned vold = (stage == 0) ? 0u : selv[b];
  if (nbins == 2048) {
    hl[t] = gh[b * 2048 + t];
    hl[t + 1024] = gh[b * 2048 + t + 1024];
  } else {
    hl[t] = gh[b * 1024 + t];
  }
  __syncthreads();
  sfx[t] = (nbins == 2048) ? (hl[2 * t] + hl[2 * t + 1]) : hl[t];
  __syncthreads();
  for (int off = 1; off < 1024; off <<= 1) {
    unsigned v = (t + off < 1024) ? sfx[t + off] : 0u;
    __syncthreads();
    sfx[t] += v;
    __syncthreads();
  }
  if ((stage != 0 && vold == SELFLAG) || sfx[0] < r) {
    if (t == 0) {
      if (stage == 2) thresh[b] = 0.0f;
      else { selv[b] = SELFLAG; selr[b] = r; }
    }
    return;
  }
  unsigned Snext = (t < 1023) ? sfx[t + 1] : 0u;
  if (nbins == 2048) {
    unsigned hi = hl[2 * t + 1], lo = hl[2 * t];
    if (Snext < r && Snext + hi >= r) {
      selv[b] = (vold << 11) | (unsigned)(2 * t + 1);
      selr[b] = r - Snext;
    } else if (Snext + hi < r && Snext + hi + lo >= r) {
      selv[b] = (vold << 11) | (unsigned)(2 * t);
      selr[b] = r - Snext - hi;
    }
  } else {
    if (Snext < r && sfx[t] >= r)
      thresh[b] = __uint_as_float((vold << 10) | (unsigned)t);
  }
}

// ---------------------------------------------------------------------------
// Kernel 4: per-pixel masked channel top-8 (jax tie-break semantics).
// Also records sparse pixels (any survivor) into per-batch compact lists.
// ---------------------------------------------------------------------------
__global__ __launch_bounds__(256) void topk_pixel_kernel(
    const float* __restrict__ A, const float* __restrict__ thresh,
    const float* __restrict__ gmaxp, float* __restrict__ out_sw,
    float* __restrict__ out_topi, int* __restrict__ kidx, float* __restrict__ kval,
    unsigned* __restrict__ ns, unsigned* __restrict__ nsw, int* __restrict__ sp_pix) {
  const int bx = blockIdx.x;              // b*4 + chunk
  const int b = bx >> 2;
  const int p = ((bx & 3) << 8) + threadIdx.x;
  const float th = thresh[b];
  const float gm = gmaxp[b];
  const float scale = gm > 0.f ? 1.f / gm : 0.f;
  const float* Ab = A + (size_t)b * (C1 * SS) + p;

  float tv0 = -1.f, tv1 = -1.f, tv2 = -1.f, tv3 = -1.f, tv4 = -1.f, tv5 = -1.f, tv6 = -1.f, tv7 = -1.f;
  int ti0 = 0, ti1 = 0, ti2 = 0, ti3 = 0, ti4 = 0, ti5 = 0, ti6 = 0, ti7 = 0;
  int cnt = 0;
#pragma unroll 1
  for (int c = 0; c < C1; ++c) {
    float v = Ab[(size_t)c << 10];
    if (v >= th) {
      ++cnt;
      bool s7 = v > tv6, p7 = (v > tv7) && !s7;
      float n7 = p7 ? v : (s7 ? tv6 : tv7); int m7 = p7 ? c : (s7 ? ti6 : ti7);
      bool s6 = v > tv5, p6 = (v > tv6) && !s6;
      float n6 = p6 ? v : (s6 ? tv5 : tv6); int m6 = p6 ? c : (s6 ? ti5 : ti6);
      bool s5 = v > tv4, p5 = (v > tv5) && !s5;
      float n5 = p5 ? v : (s5 ? tv4 : tv5); int m5 = p5 ? c : (s5 ? ti4 : ti5);
      bool s4 = v > tv3, p4 = (v > tv4) && !s4;
      float n4 = p4 ? v : (s4 ? tv3 : tv4); int m4 = p4 ? c : (s4 ? ti3 : ti4);
      bool s3 = v > tv2, p3 = (v > tv3) && !s3;
      float n3 = p3 ? v : (s3 ? tv2 : tv3); int m3 = p3 ? c : (s3 ? ti2 : ti3);
      bool s2 = v > tv1, p2 = (v > tv2) && !s2;
      float n2 = p2 ? v : (s2 ? tv1 : tv2); int m2 = p2 ? c : (s2 ? ti1 : ti2);
      bool s1 = v > tv0, p1 = (v > tv1) && !s1;
      float n1 = p1 ? v : (s1 ? tv0 : tv1); int m1 = p1 ? c : (s1 ? ti0 : ti1);
      bool p0 = v > tv0;
      float n0 = p0 ? v : tv0; int m0 = p0 ? c : ti0;
      tv7 = n7; ti7 = m7; tv6 = n6; ti6 = m6; tv5 = n5; ti5 = m5; tv4 = n4; ti4 = m4;
      tv3 = n3; ti3 = m3; tv2 = n2; ti2 = m2; tv1 = n1; ti1 = m1; tv0 = n0; ti0 = m0;
    }
  }
  const int m = cnt < 8 ? cnt : 8;
  // record sparse pixel
  if (cnt > 0) {
    unsigned slot = atomicAdd(&ns[b], 1u);
    if (slot < (unsigned)SCAP) {
      sp_pix[b * SCAP + slot] = p;
      atomicAdd(&nsw[b * 32 + (p & 31)], 1u);
    }
  }
  int fv[8] = {ti0, ti1, ti2, ti3, ti4, ti5, ti6, ti7};
  int fill_c = 0;
#pragma unroll
  for (int j = 0; j < 8; ++j) {
    if (j >= m) {
      bool adv = true;
      while (adv) {
        adv = false;
#pragma unroll
        for (int t2 = 0; t2 < 8; ++t2)
          if (t2 < m && fv[t2] == fill_c) adv = true;
        if (adv) ++fill_c;
      }
      fv[j] = fill_c;
      ++fill_c;
    }
  }
  ti0 = fv[0]; ti1 = fv[1]; ti2 = fv[2]; ti3 = fv[3]; ti4 = fv[4]; ti5 = fv[5]; ti6 = fv[6]; ti7 = fv[7];
  if (m <= 0) tv0 = 0.f; if (m <= 1) tv1 = 0.f; if (m <= 2) tv2 = 0.f; if (m <= 3) tv3 = 0.f;
  if (m <= 4) tv4 = 0.f; if (m <= 5) tv5 = 0.f; if (m <= 6) tv6 = 0.f; if (m <= 7) tv7 = 0.f;

  const size_t pix = (size_t)b * SS + p;
  float* tp = out_topi + pix * 8;
  tp[0] = (float)ti0; tp[1] = (float)ti1; tp[2] = (float)ti2; tp[3] = (float)ti3;
  tp[4] = (float)ti4; tp[5] = (float)ti5; tp[6] = (float)ti6; tp[7] = (float)ti7;
  int* ki = kidx + pix * 8;
  ki[0] = ti0; ki[1] = ti1; ki[2] = ti2; ki[3] = ti3; ki[4] = ti4; ki[5] = ti5; ki[6] = ti6; ki[7] = ti7;
  float* kv = kval + pix * 8;
  float sv0 = tv0 * scale, sv1 = tv1 * scale, sv2 = tv2 * scale, sv3 = tv3 * scale;
  float sv4 = tv4 * scale, sv5 = tv5 * scale, sv6 = tv6 * scale, sv7 = tv7 * scale;
  kv[0] = sv0; kv[1] = sv1; kv[2] = sv2; kv[3] = sv3; kv[4] = sv4; kv[5] = sv5; kv[6] = sv6; kv[7] = sv7;
  float* sw = out_sw + pix * C1;
  if (m > 0) sw[ti0] = sv0; if (m > 1) sw[ti1] = sv1; if (m > 2) sw[ti2] = sv2; if (m > 3) sw[ti3] = sv3;
  if (m > 4) sw[ti4] = sv4; if (m > 5) sw[ti5] = sv5; if (m > 6) sw[ti6] = sv6; if (m > 7) sw[ti7] = sv7;
}

// ---------------------------------------------------------------------------
// Kernel 5: PEQKV[w][0:768] = PE-row(w) @ in_proj_w^T + in_proj_b  (32 rows)
// ---------------------------------------------------------------------------
__global__ __launch_bounds__(256) void pe_qkv_kernel(
    const float* __restrict__ ipw, const float* __restrict__ ipb,
    float* __restrict__ PEQKV) {
  const int w = blockIdx.x;               // 0..31
  const int t = threadIdx.x;
  __shared__ __align__(16) float pe[256];
  {
    int i2 = t >> 1;
    float dv = expf((float)(2 * i2) * (-9.210340371976184f / 256.f));
    float ang = (float)w * dv;
    pe[t] = (t & 1) ? cosf(ang) : sinf(ang);
  }
  __syncthreads();
  const float4* pe4 = (const float4*)pe;
#pragma unroll 1
  for (int o = t; o < TRIPLE; o += 256) {
    const float4* wr = (const float4*)&ipw[(size_t)o * DD];
    float acc = ipb[o];
#pragma unroll 16
    for (int k = 0; k < 64; ++k) {
      float4 a = pe4[k], bq = wr[k];
      acc += a.x * bq.x + a.y * bq.y + a.z * bq.z + a.w * bq.w;
    }
    PEQKV[(size_t)w * TRIPLE + o] = acc;
  }
}

// ---------------------------------------------------------------------------
// Kernel 6: gather sparse-token embedding mixes into E (compact rows),
// and emit glist metadata for the GEMM scatter epilogue.
// ---------------------------------------------------------------------------
__global__ __launch_bounds__(256) void emb_gather_kernel(
    const unsigned* __restrict__ ns, const int* __restrict__ sp_pix,
    const int* __restrict__ kidx, const float* __restrict__ kval,
    const float* __restrict__ emb, float* __restrict__ E,
    unsigned* __restrict__ glist) {
  const int bx = blockIdx.x;              // b*SCAP + i
  const int b = bx >> 7, i = bx & (SCAP - 1);
  const unsigned nsb = ns[b] < (unsigned)SCAP ? ns[b] : (unsigned)SCAP;
  if ((unsigned)i >= nsb) return;
  const int p = sp_pix[b * SCAP + i];
  const int d = threadIdx.x;
  const int* ki = kidx + ((size_t)b * SS + p) * 8;
  const float* kv = kval + ((size_t)b * SS + p) * 8;
  float e = 0.f;
#pragma unroll
  for (int j = 0; j < 8; ++j) e += kv[j] * emb[(size_t)ki[j] * DD + d];
  E[(size_t)bx * DD + d] = e;
  if (d == 0) glist[bx] = ((unsigned)b << 16) | ((unsigned)i << 8) | (unsigned)(p & 31);
}

// ---------------------------------------------------------------------------
// Kernel 7: SQKV scatter-GEMM: for valid rows r (glist[r]!=-1):
//   SQKV[b][i][col] = (E[r] @ W^T)[col] + PEQKV[w][col]     (no bias; PEQKV has it)
// MFMA bf16, 128x128 tiles, K=256.
// ---------------------------------------------------------------------------
__global__ __launch_bounds__(256) void eqkv_gemm_kernel(
    const float* __restrict__ E, const float* __restrict__ W,
    const unsigned* __restrict__ glist, const float* __restrict__ PEQKV,
    float* __restrict__ SQKV) {
  __shared__ __align__(16) short As[128][40];
  __shared__ __align__(16) short Bs[128][40];
  const int mt = blockIdx.x / 6, nt = blockIdx.x % 6;   // 32 x 6
  const int t = threadIdx.x;
  const int wv = t >> 6, lane = t & 63, lg = lane >> 4, ln = lane & 15;
  const int wm = wv >> 1, wn = wv & 1;

  f32x4 acc[4][4];
#pragma unroll
  for (int i = 0; i < 4; ++i)
#pragma unroll
    for (int j = 0; j < 4; ++j) acc[i][j] = (f32x4){0, 0, 0, 0};

  for (int k0 = 0; k0 < DD; k0 += 32) {
    __syncthreads();
    for (int f = t; f < 1024; f += 256) {
      int row = f >> 3, q4 = (f & 7) * 4;
      float4 xa = *(const float4*)&E[(size_t)(mt * 128 + row) * DD + k0 + q4];
      float4 wa = *(const float4*)&W[(size_t)(nt * 128 + row) * DD + k0 + q4];
      short* ad = &As[row][q4];
      ad[0] = f2bf(xa.x); ad[1] = f2bf(xa.y); ad[2] = f2bf(xa.z); ad[3] = f2bf(xa.w);
      short* bd = &Bs[row][q4];
      bd[0] = f2bf(wa.x); bd[1] = f2bf(wa.y); bd[2] = f2bf(wa.z); bd[3] = f2bf(wa.w);
    }
    __syncthreads();
    bf16x8 af[4], bfr[4];
#pragma unroll
    for (int i = 0; i < 4; ++i) af[i] = *(const bf16x8*)&As[wm * 64 + i * 16 + ln][lg * 8];
#pragma unroll
    for (int j = 0; j < 4; ++j) bfr[j] = *(const bf16x8*)&Bs[wn * 64 + j * 16 + ln][lg * 8];
#pragma unroll
    for (int i = 0; i < 4; ++i)
#pragma unroll
      for (int j = 0; j < 4; ++j)
        acc[i][j] = __builtin_amdgcn_mfma_f32_16x16x32_bf16(af[i], bfr[j], acc[i][j], 0, 0, 0);
  }
#pragma unroll
  for (int i = 0; i < 4; ++i) {
#pragma unroll
    for (int r = 0; r < 4; ++r) {
      int row = mt * 128 + wm * 64 + i * 16 + lg * 4 + r;
      unsigned meta = glist[row];
      if (meta == 0xFFFFFFFFu) continue;
      int b = meta >> 16, ii = (meta >> 8) & 255, w = meta & 255;
#pragma unroll
      for (int j = 0; j < 4; ++j) {
        int col = nt * 128 + wn * 64 + j * 16 + ln;
        SQKV[((size_t)(b * SCAP) + ii) * TRIPLE + col] =
            acc[i][j][r] + PEQKV[(size_t)w * TRIPLE + col];
      }
    }
  }
}

// ---------------------------------------------------------------------------
// Kernel 8: compressed attention over distinct tokens with multiplicities.
// Block = (b, h); D = 32 + ns[b] tokens; K/V head-slices staged in LDS fp32.
// ctx_sum[b][h*32+d] += sum_q c_q * ctx_q[d]  (count-weighted online softmax)
// ---------------------------------------------------------------------------
__global__ __launch_bounds__(256) void attn_small_kernel(
    const float* __restrict__ PEQKV, const float* __restrict__ SQKV,
    const unsigned* __restrict__ ns, const unsigned* __restrict__ nsw,
    float* __restrict__ ctx_sum) {
  const int b = blockIdx.x >> 3, h = blockIdx.x & 7;
  const int t = threadIdx.x;
  __shared__ float Kh[DMAX][32];
  __shared__ float Vh[DMAX][32];
  __shared__ float cw[DMAX];
  const unsigned nsb = ns[b] < (unsigned)SCAP ? ns[b] : (unsigned)SCAP;
  const int D = 32 + (int)nsb;
  const int hoff = h * DHH;

  for (int idx = t; idx < D * 32; idx += 256) {
    int j = idx >> 5, d = idx & 31;
    const float* src = (j < 32) ? &PEQKV[(size_t)j * TRIPLE]
                                : &SQKV[((size_t)(b * SCAP) + (j - 32)) * TRIPLE];
    Kh[j][d] = src[DD + hoff + d];
    Vh[j][d] = src[2 * DD + hoff + d];
  }
  if (t < D) cw[t] = (t < 32) ? (float)(32 - (int)nsw[b * 32 + t]) : 1.0f;
  __syncthreads();

  float acc[32];
#pragma unroll
  for (int d = 0; d < 32; ++d) acc[d] = 0.f;
  float wq = 0.f;

  if (t < D) {
    const float* qsrc = (t < 32) ? &PEQKV[(size_t)t * TRIPLE]
                                 : &SQKV[((size_t)(b * SCAP) + (t - 32)) * TRIPLE];
    const float qsc = 0.25506973f;          // (1/sqrt(32)) * log2(e)
    float qv[32];
#pragma unroll
    for (int d = 0; d < 32; ++d) qv[d] = qsrc[hoff + d] * qsc;
    float m = -1e30f, l = 0.f;
#pragma unroll 1
    for (int j = 0; j < D; ++j) {
      float s = 0.f;
      const float* kr = &Kh[j][0];
#pragma unroll
      for (int d = 0; d < 32; ++d) s += qv[d] * kr[d];
      if (s > m) {
        float corr = exp2f(m - s);
        l *= corr;
#pragma unroll
        for (int d = 0; d < 32; ++d) acc[d] *= corr;
        m = s;
      }
      float p = cw[j] * exp2f(s - m);
      l += p;
      const float* vr = &Vh[j][0];
#pragma unroll
      for (int d = 0; d < 32; ++d) acc[d] += p * vr[d];
    }
    wq = cw[t] / l;
  }
  // reduce c_q * ctx_q over the wave, one atomic per (wave, d)
  float* cbase = &ctx_sum[b * DD + hoff];
#pragma unroll 1
  for (int d = 0; d < 32; ++d) {
    float val = wq * acc[d];
    val += __shfl_xor(val, 1);  val += __shfl_xor(val, 2);
    val += __shfl_xor(val, 4);  val += __shfl_xor(val, 8);
    val += __shfl_xor(val, 16); val += __shfl_xor(val, 32);
    if ((t & 63) == 0) atomicAdd(cbase + d, val);
  }
}

// ---------------------------------------------------------------------------
// Kernel 9: pooled(b,o) = bias[o] + sum_d (ctx_sum[b,d]/1024) * Wout[o,d]
// ---------------------------------------------------------------------------
__global__ __launch_bounds__(256) void pooled_kernel(
    const float* __restrict__ ctx_sum, const float* __restrict__ Wout,
    const float* __restrict__ bout, float* __restrict__ out) {
  const int b = blockIdx.x;
  const int o = threadIdx.x;
  __shared__ float mc[DD];
  mc[o] = ctx_sum[b * DD + o] * (1.f / 1024.f);
  __syncthreads();
  float acc = bout[o];
  const float* wr = Wout + (size_t)o * DD;
#pragma unroll 4
  for (int d = 0; d < DD; ++d) acc += mc[d] * wr[d];
  out[b * DD + o] = acc;
}

// ---------------------------------------------------------------------------
extern "C" void kernel_launch(void* const* d_in, const int* in_sizes, int n_in,
                              void* d_out, int out_size, void* d_ws, size_t ws_size,
                              hipStream_t stream) {
  const float* x = (const float*)d_in[0];
  const float* conv_w = (const float*)d_in[1];
  const float* emb = (const float*)d_in[2];
  const float* ipw = (const float*)d_in[3];
  const float* ipb = (const float*)d_in[4];
  const float* opw = (const float*)d_in[5];
  const float* opb = (const float*)d_in[6];

  float* out = (float*)d_out;
  float* out_pooled = out;                          // 32*256       = 8192
  float* out_sw = out + 8192;                       // 32*32*32*128 = 4194304
  float* out_topi = out + 8192 + 4194304;           // 32*32*32*8   = 262144

  // workspace layout (~37 MiB)
  char* ws = (char*)d_ws;
  float*    A      = (float*)(ws);                      // 16777216
  unsigned* ghist1 = (unsigned*)(ws + 16777216);        // 262144
  unsigned* ghist2 = (unsigned*)(ws + 17039360);        // 262144
  unsigned* ghist3 = (unsigned*)(ws + 17301504);        // 131072
  unsigned* selv   = (unsigned*)(ws + 17432576);        // 128
  unsigned* selr   = (unsigned*)(ws + 17432704);        // 128
  float*    thresh = (float*)(ws + 17432832);           // 128
  unsigned* gmaxb  = (unsigned*)(ws + 17432960);        // 128
  unsigned* nsp    = (unsigned*)(ws + 17433088);        // 128
  unsigned* nsw    = (unsigned*)(ws + 17433216);        // 4096
  int*      sp_pix = (int*)(ws + 17437312);             // 16384
  unsigned* glist  = (unsigned*)(ws + 17453696);        // 16384
  int*      kidx   = (int*)(ws + 17470080);             // 1048576
  float*    kval   = (float*)(ws + 18518656);           // 1048576
  float*    PEQKV  = (float*)(ws + 19567232);           // 98304
  float*    E      = (float*)(ws + 19665536);           // 4194304
  float*    SQKV   = (float*)(ws + 23859840);           // 12582912
  float*    ctx    = (float*)(ws + 36442752);           // 32768

  hipMemsetAsync(out_sw, 0, (size_t)4194304 * 4, stream);
  hipMemsetAsync(ws + 16777216, 0, 660096, stream);     // hists + sel + ns + nsw
  hipMemsetAsync(glist, 0xFF, 16384, stream);
  hipMemsetAsync(ctx, 0, (size_t)BB * DD * 4, stream);

  conv_relu_hist_kernel<<<BB * C1, 256, 0, stream>>>(x, conv_w, A, ghist1, gmaxb);
  sel_kernel<<<BB, 1024, 0, stream>>>(ghist1, selv, selr, thresh, 2048, 0);
  hist2_kernel<<<dim3(16, BB), 256, 0, stream>>>(A, selv, ghist2);
  sel_kernel<<<BB, 1024, 0, stream>>>(ghist2, selv, selr, thresh, 2048, 1);
  hist3_kernel<<<dim3(16, BB), 256, 0, stream>>>(A, selv, ghist3);
  sel_kernel<<<BB, 1024, 0, stream>>>(ghist3, selv, selr, thresh, 1024, 2);
  topk_pixel_kernel<<<BB * 4, 256, 0, stream>>>(A, thresh, (const float*)gmaxb,
                                                out_sw, out_topi, kidx, kval,
                                                nsp, nsw, sp_pix);
  pe_qkv_kernel<<<32, 256, 0, stream>>>(ipw, ipb, PEQKV);
  emb_gather_kernel<<<BB * SCAP, 256, 0, stream>>>(nsp, sp_pix, kidx, kval, emb, E, glist);
  eqkv_gemm_kernel<<<32 * 6, 256, 0, stream>>>(E, ipw, glist, PEQKV, SQKV);
  attn_small_kernel<<<BB * NHH, 256, 0, stream>>>(PEQKV, SQKV, nsp, nsw, ctx);
  pooled_kernel<<<BB, 256, 0, stream>>>(ctx, opw, opb, out_pooled);
}